// Round 9
// baseline (633.488 us; speedup 1.0000x reference)
//
#include <hip/hip_runtime.h>
#include <hip/hip_bf16.h>

#define NEG_SLOPE 0.2f
#define LOG2E 1.44269504088896f

typedef _Float16 half8 __attribute__((ext_vector_type(8)));
typedef _Float16 half4 __attribute__((ext_vector_type(4)));
typedef _Float16 half2t __attribute__((ext_vector_type(2)));
typedef float floatx2 __attribute__((ext_vector_type(2)));

__device__ __forceinline__ void ld4(float* d, const float* p) {
    float4 t = *(const float4*)p;
    d[0] = t.x; d[1] = t.y; d[2] = t.z; d[3] = t.w;
}

__device__ __forceinline__ unsigned pack2h(float a, float b) {
    union { half2t h; unsigned u; } pk;
    pk.h[0] = (_Float16)a; pk.h[1] = (_Float16)b;
    return pk.u;
}

// full-rate VALU 16-lane-row all-reduce stage (no DS pipe)
#define DPP_ADD(x, ctrl) \
    ((x) + __int_as_float(__builtin_amdgcn_update_dpp(0, __float_as_int(x), (ctrl), 0xf, 0xf, true)))
#define ROW_REDUCE16(x) do { \
    x = DPP_ADD(x, 0x128); \
    x = DPP_ADD(x, 0x124); \
    x = DPP_ADD(x, 0x122); \
    x = DPP_ADD(x, 0x121); \
} while (0)

// ---------------------------------------------------------------------------
// PREP: layer-1 source+target transforms -> fp16 interleaved tables + histogram.
// ---------------------------------------------------------------------------
__global__ void __launch_bounds__(256) prep_kernel(
    const float* __restrict__ x,
    const float* __restrict__ Wl1, const float* __restrict__ bl1,
    const float* __restrict__ Wr1, const float* __restrict__ br1,
    _Float16* __restrict__ xlh, _Float16* __restrict__ xrh,
    const int* __restrict__ dstv, int* __restrict__ deg,
    int N, int E)
{
    int gt = blockIdx.x * blockDim.x + threadIdx.x;
    int total = blockDim.x * gridDim.x;
    for (int e = gt; e < E; e += total) atomicAdd(&deg[dstv[e]], 1);
    int n = gt >> 6, c = gt & 63;
    if (n >= N) return;
    const float* xrow = x + (size_t)n * 6;
    float l0 = bl1[c], l1 = bl1[64 + c];
    float r0 = br1[c], r1 = br1[64 + c];
#pragma unroll
    for (int f = 0; f < 6; ++f) {
        float xv = xrow[f];
        l0 = fmaf(xv, Wl1[f * 128 + c], l0);
        l1 = fmaf(xv, Wl1[f * 128 + 64 + c], l1);
        r0 = fmaf(xv, Wr1[f * 128 + c], r0);
        r1 = fmaf(xv, Wr1[f * 128 + 64 + c], r1);
    }
    *(unsigned*)(xlh + (size_t)n * 128 + 2 * c) = pack2h(l0, l1);
    *(unsigned*)(xrh + (size_t)n * 128 + 2 * c) = pack2h(r0, r1);
}

// ---------------------------------------------------------------------------
// CSR build: scan + scatter (8B packed edges)
// ---------------------------------------------------------------------------
__global__ void scan1_kernel(const int* __restrict__ deg, int* __restrict__ bsum, int N) {
    __shared__ int red[256];
    int b = blockIdx.x, t = threadIdx.x;
    int i0 = b * 512 + t, i1 = i0 + 256;
    int v = 0;
    if (i0 < N) v += deg[i0];
    if (i1 < N) v += deg[i1];
    red[t] = v;
    __syncthreads();
    for (int s = 128; s > 0; s >>= 1) {
        if (t < s) red[t] += red[t + s];
        __syncthreads();
    }
    if (t == 0) bsum[b] = red[0];
}

__global__ void scan2_kernel(const int* __restrict__ bsum, int* __restrict__ bpref,
                             int* __restrict__ off, int B, int N) {
    __shared__ int lds[1024];
    int t = threadIdx.x;
    for (int i = t; i < B; i += blockDim.x) lds[i] = bsum[i];
    __syncthreads();
    if (t == 0) {
        int run = 0;
        for (int i = 0; i < B; ++i) { int v = lds[i]; lds[i] = run; run += v; }
        off[N] = run;
    }
    __syncthreads();
    for (int i = t; i < B; i += blockDim.x) bpref[i] = lds[i];
}

__global__ void scan3_kernel(const int* __restrict__ deg, const int* __restrict__ bpref,
                             int* __restrict__ off, int* __restrict__ pos, int N) {
    __shared__ int lds[512];
    int b = blockIdx.x, t = threadIdx.x;
    int base = b * 512;
    for (int i = t; i < 512; i += 256) {
        int g = base + i;
        lds[i] = (g < N) ? deg[g] : 0;
    }
    __syncthreads();
    if (t == 0) {
        int run = bpref[b];
        for (int i = 0; i < 512; ++i) { int v = lds[i]; lds[i] = run; run += v; }
    }
    __syncthreads();
    for (int i = t; i < 512; i += 256) {
        int g = base + i;
        if (g < N) { off[g] = lds[i]; pos[g] = lds[i]; }
    }
}

__global__ void scatter_kernel(const int* __restrict__ srcv, const int* __restrict__ dstv,
                               const float2* __restrict__ ea2, int* __restrict__ pos,
                               int2* __restrict__ csr_edge, int E) {
    int e = blockIdx.x * blockDim.x + threadIdx.x;
    if (e >= E) return;
    int d = dstv[e];
    int p = atomicAdd(&pos[d], 1);
    float2 ea = ea2[e];
    int2 v;
    v.x = srcv[e];
    v.y = (int)pack2h(ea.x, ea.y);
    csr_edge[p] = v;
}

// ---------------------------------------------------------------------------
// C1: layer-1 aggregation. Persistent waves: grid-stride over dst nodes;
// weights loaded once per wave. 8 edges/iter (2 quads x 16 lanes/edge).
// ---------------------------------------------------------------------------
__global__ void __launch_bounds__(256) c1_kernel(
    const int* __restrict__ off, const int2* __restrict__ csr_edge,
    const _Float16* __restrict__ xlh, const _Float16* __restrict__ xrh,
    const float* __restrict__ We1, const float* __restrict__ att1,
    const float* __restrict__ bias1,
    float* __restrict__ h1, int N)
{
    int lane = threadIdx.x & 63;
    int g = lane & 15;
    int slot = lane >> 4;
    int wslot = (blockIdx.x * blockDim.x + threadIdx.x) >> 6;
    int nwaves = (gridDim.x * blockDim.x) >> 6;

    // per-wave constants (loaded once)
    floatx2 a0v[2], a1v[2], w00v[2], w01v[2], w10v[2], w11v[2];
    float b0[4], b1[4];
    {
        float t[4];
        ld4(t, att1 + 4 * g);
        a0v[0] = floatx2{t[0], t[1]} * (floatx2)LOG2E; a0v[1] = floatx2{t[2], t[3]} * (floatx2)LOG2E;
        ld4(t, att1 + 64 + 4 * g);
        a1v[0] = floatx2{t[0], t[1]} * (floatx2)LOG2E; a1v[1] = floatx2{t[2], t[3]} * (floatx2)LOG2E;
        ld4(t, We1 + 4 * g);        w00v[0] = floatx2{t[0], t[1]}; w00v[1] = floatx2{t[2], t[3]};
        ld4(t, We1 + 64 + 4 * g);   w01v[0] = floatx2{t[0], t[1]}; w01v[1] = floatx2{t[2], t[3]};
        ld4(t, We1 + 128 + 4 * g);  w10v[0] = floatx2{t[0], t[1]}; w10v[1] = floatx2{t[2], t[3]};
        ld4(t, We1 + 192 + 4 * g);  w11v[0] = floatx2{t[0], t[1]}; w11v[1] = floatx2{t[2], t[3]};
        ld4(b0, bias1 + 4 * g);
        ld4(b1, bias1 + 64 + 4 * g);
    }

    for (int n = wslot; n < N; n += nwaves) {
        floatx2 xr0v[2], xr1v[2];
        {
            half8 xrv = *(const half8*)(xrh + (size_t)n * 128 + 8 * g);
            xr0v[0] = floatx2{(float)xrv[0], (float)xrv[2]};
            xr0v[1] = floatx2{(float)xrv[4], (float)xrv[6]};
            xr1v[0] = floatx2{(float)xrv[1], (float)xrv[3]};
            xr1v[1] = floatx2{(float)xrv[5], (float)xrv[7]};
        }

        int s = off[n], e = off[n + 1];
        floatx2 acc0A[2] = {floatx2{0,0}, floatx2{0,0}}, acc1A[2] = {floatx2{0,0}, floatx2{0,0}};
        floatx2 acc0B[2] = {floatx2{0,0}, floatx2{0,0}}, acc1B[2] = {floatx2{0,0}, floatx2{0,0}};
        float d0A = 0.f, d1A = 0.f, d0B = 0.f, d1B = 0.f;

        for (int p0 = s; p0 < e; p0 += 8) {
            int pA = p0 + slot;
            int pB = p0 + 4 + slot;
            bool vA = (pA < e), vB = (pB < e);
            int2 edA = csr_edge[vA ? pA : s];
            int2 edB = csr_edge[vB ? pB : s];
            union { int u; half2t h; } eAu, eBu;
            eAu.u = edA.y; eBu.u = edB.y;
            float eaxA = (float)eAu.h[0], eayA = (float)eAu.h[1];
            float eaxB = (float)eBu.h[0], eayB = (float)eBu.h[1];

            half8 hvA = *(const half8*)(xlh + (size_t)edA.x * 128 + 8 * g);
            half8 hvB = *(const half8*)(xlh + (size_t)edB.x * 128 + 8 * g);

            floatx2 xl0A[2], xl1A[2], xl0B[2], xl1B[2];
            xl0A[0] = floatx2{(float)hvA[0], (float)hvA[2]};
            xl0A[1] = floatx2{(float)hvA[4], (float)hvA[6]};
            xl1A[0] = floatx2{(float)hvA[1], (float)hvA[3]};
            xl1A[1] = floatx2{(float)hvA[5], (float)hvA[7]};
            xl0B[0] = floatx2{(float)hvB[0], (float)hvB[2]};
            xl0B[1] = floatx2{(float)hvB[4], (float)hvB[6]};
            xl1B[0] = floatx2{(float)hvB[1], (float)hvB[3]};
            xl1B[1] = floatx2{(float)hvB[5], (float)hvB[7]};

            floatx2 pv0A = floatx2{0,0}, pv1A = floatx2{0,0};
            floatx2 pv0B = floatx2{0,0}, pv1B = floatx2{0,0};
#pragma unroll
            for (int k = 0; k < 2; ++k) {
                floatx2 z;
                z = xl0A[k] + xr0v[k];
                z = __builtin_elementwise_fma((floatx2)eaxA, w00v[k], z);
                z = __builtin_elementwise_fma((floatx2)eayA, w10v[k], z);
                z = __builtin_elementwise_max(z, z * (floatx2)NEG_SLOPE);
                pv0A = __builtin_elementwise_fma(z, a0v[k], pv0A);

                z = xl1A[k] + xr1v[k];
                z = __builtin_elementwise_fma((floatx2)eaxA, w01v[k], z);
                z = __builtin_elementwise_fma((floatx2)eayA, w11v[k], z);
                z = __builtin_elementwise_max(z, z * (floatx2)NEG_SLOPE);
                pv1A = __builtin_elementwise_fma(z, a1v[k], pv1A);

                z = xl0B[k] + xr0v[k];
                z = __builtin_elementwise_fma((floatx2)eaxB, w00v[k], z);
                z = __builtin_elementwise_fma((floatx2)eayB, w10v[k], z);
                z = __builtin_elementwise_max(z, z * (floatx2)NEG_SLOPE);
                pv0B = __builtin_elementwise_fma(z, a0v[k], pv0B);

                z = xl1B[k] + xr1v[k];
                z = __builtin_elementwise_fma((floatx2)eaxB, w01v[k], z);
                z = __builtin_elementwise_fma((floatx2)eayB, w11v[k], z);
                z = __builtin_elementwise_max(z, z * (floatx2)NEG_SLOPE);
                pv1B = __builtin_elementwise_fma(z, a1v[k], pv1B);
            }
            float pA0 = pv0A.x + pv0A.y;
            float pA1 = pv1A.x + pv1A.y;
            float pB0 = pv0B.x + pv0B.y;
            float pB1 = pv1B.x + pv1B.y;

            ROW_REDUCE16(pA0);
            ROW_REDUCE16(pA1);
            ROW_REDUCE16(pB0);
            ROW_REDUCE16(pB1);

            float eA0 = vA ? exp2f(pA0) : 0.f;
            float eA1 = vA ? exp2f(pA1) : 0.f;
            float eB0 = vB ? exp2f(pB0) : 0.f;
            float eB1 = vB ? exp2f(pB1) : 0.f;
            d0A += eA0; d1A += eA1;
            d0B += eB0; d1B += eB1;
#pragma unroll
            for (int k = 0; k < 2; ++k) {
                acc0A[k] = __builtin_elementwise_fma((floatx2)eA0, xl0A[k], acc0A[k]);
                acc1A[k] = __builtin_elementwise_fma((floatx2)eA1, xl1A[k], acc1A[k]);
                acc0B[k] = __builtin_elementwise_fma((floatx2)eB0, xl0B[k], acc0B[k]);
                acc1B[k] = __builtin_elementwise_fma((floatx2)eB1, xl1B[k], acc1B[k]);
            }
        }

        float acc0[4], acc1[4];
        acc0[0] = acc0A[0].x + acc0B[0].x;  acc0[1] = acc0A[0].y + acc0B[0].y;
        acc0[2] = acc0A[1].x + acc0B[1].x;  acc0[3] = acc0A[1].y + acc0B[1].y;
        acc1[0] = acc1A[0].x + acc1B[0].x;  acc1[1] = acc1A[0].y + acc1B[0].y;
        acc1[2] = acc1A[1].x + acc1B[1].x;  acc1[3] = acc1A[1].y + acc1B[1].y;
        float d0 = d0A + d0B, d1 = d1A + d1B;
#pragma unroll
        for (int i = 0; i < 4; ++i) {
            acc0[i] += __shfl_xor(acc0[i], 16); acc0[i] += __shfl_xor(acc0[i], 32);
            acc1[i] += __shfl_xor(acc1[i], 16); acc1[i] += __shfl_xor(acc1[i], 32);
        }
        d0 += __shfl_xor(d0, 16); d0 += __shfl_xor(d0, 32);
        d1 += __shfl_xor(d1, 16); d1 += __shfl_xor(d1, 32);

        if (slot == 0) {
            float r0 = 1.f / (d0 + 1e-16f), r1 = 1.f / (d1 + 1e-16f);
            float4 o0, o1;
            o0.x = fmaxf(fmaf(acc0[0], r0, b0[0]), 0.f);
            o0.y = fmaxf(fmaf(acc0[1], r0, b0[1]), 0.f);
            o0.z = fmaxf(fmaf(acc0[2], r0, b0[2]), 0.f);
            o0.w = fmaxf(fmaf(acc0[3], r0, b0[3]), 0.f);
            o1.x = fmaxf(fmaf(acc1[0], r1, b1[0]), 0.f);
            o1.y = fmaxf(fmaf(acc1[1], r1, b1[1]), 0.f);
            o1.z = fmaxf(fmaf(acc1[2], r1, b1[2]), 0.f);
            o1.w = fmaxf(fmaf(acc1[3], r1, b1[3]), 0.f);
            *(float4*)(h1 + (size_t)n * 128 + 4 * g) = o0;
            *(float4*)(h1 + (size_t)n * 128 + 64 + 4 * g) = o1;
        }
    }
}

// ---------------------------------------------------------------------------
// A2: layer-2 node transforms as an LDS-tiled GEMM (no shuffles).
// ---------------------------------------------------------------------------
__global__ void __launch_bounds__(256) a2_kernel(
    const float* __restrict__ h1,
    const float* __restrict__ Wl2, const float* __restrict__ bl2,
    const float* __restrict__ Wr2, const float* __restrict__ br2,
    _Float16* __restrict__ xl2h, _Float16* __restrict__ xr2h, int N)
{
    __shared__ float hs[64 * 128];   // 32 KB
    int tid = threadIdx.x;
    int n0 = blockIdx.x * 64;

    for (int i = tid; i < 64 * 32; i += 256) {
        int row = i >> 5;
        int q = i & 31;
        int n = n0 + row;
        float4 v = (n < N) ? *(const float4*)(h1 + (size_t)n * 128 + q * 4)
                           : make_float4(0.f, 0.f, 0.f, 0.f);
        *(float4*)(hs + row * 128 + q * 4) = v;
    }
    __syncthreads();

    int cslot = tid & 31;
    int jgrp = tid >> 5;
    int c4 = cslot * 4;
    bool isL = (c4 < 64);
    int cc = isL ? c4 : (c4 - 64);
    const float* Wb = (isL ? Wl2 : Wr2) + cc;
    const float* bb = (isL ? bl2 : br2) + cc;
    float4 bias = *(const float4*)bb;

    float acc[8][4];
#pragma unroll
    for (int j = 0; j < 8; ++j) {
        acc[j][0] = bias.x; acc[j][1] = bias.y;
        acc[j][2] = bias.z; acc[j][3] = bias.w;
    }

    const float* hrow = hs + (jgrp * 8) * 128;
#pragma unroll 2
    for (int k4 = 0; k4 < 32; ++k4) {
        float4 w0 = *(const float4*)(Wb + (4 * k4 + 0) * 64);
        float4 w1 = *(const float4*)(Wb + (4 * k4 + 1) * 64);
        float4 w2 = *(const float4*)(Wb + (4 * k4 + 2) * 64);
        float4 w3 = *(const float4*)(Wb + (4 * k4 + 3) * 64);
#pragma unroll
        for (int j = 0; j < 8; ++j) {
            float4 hv = *(const float4*)(hrow + j * 128 + k4 * 4);
            acc[j][0] = fmaf(hv.x, w0.x, acc[j][0]);
            acc[j][1] = fmaf(hv.x, w0.y, acc[j][1]);
            acc[j][2] = fmaf(hv.x, w0.z, acc[j][2]);
            acc[j][3] = fmaf(hv.x, w0.w, acc[j][3]);
            acc[j][0] = fmaf(hv.y, w1.x, acc[j][0]);
            acc[j][1] = fmaf(hv.y, w1.y, acc[j][1]);
            acc[j][2] = fmaf(hv.y, w1.z, acc[j][2]);
            acc[j][3] = fmaf(hv.y, w1.w, acc[j][3]);
            acc[j][0] = fmaf(hv.z, w2.x, acc[j][0]);
            acc[j][1] = fmaf(hv.z, w2.y, acc[j][1]);
            acc[j][2] = fmaf(hv.z, w2.z, acc[j][2]);
            acc[j][3] = fmaf(hv.z, w2.w, acc[j][3]);
            acc[j][0] = fmaf(hv.w, w3.x, acc[j][0]);
            acc[j][1] = fmaf(hv.w, w3.y, acc[j][1]);
            acc[j][2] = fmaf(hv.w, w3.z, acc[j][2]);
            acc[j][3] = fmaf(hv.w, w3.w, acc[j][3]);
        }
    }

    _Float16* outb = isL ? xl2h : xr2h;
#pragma unroll
    for (int j = 0; j < 8; ++j) {
        int n = n0 + jgrp * 8 + j;
        if (n < N) {
            half4 o;
            o[0] = (_Float16)acc[j][0];
            o[1] = (_Float16)acc[j][1];
            o[2] = (_Float16)acc[j][2];
            o[3] = (_Float16)acc[j][3];
            *(half4*)(outb + (size_t)n * 64 + cc) = o;
        }
    }
}

// ---------------------------------------------------------------------------
// C2: layer-2 aggregation + fused MLP head. Persistent waves (grid-stride).
// ---------------------------------------------------------------------------
__global__ void __launch_bounds__(256) c2_kernel(
    const int* __restrict__ off, const int2* __restrict__ csr_edge,
    const _Float16* __restrict__ xl2h, const _Float16* __restrict__ xr2h,
    const float* __restrict__ We2, const float* __restrict__ att2,
    const float* __restrict__ bias2,
    const float* __restrict__ Wh1, const float* __restrict__ bh1,
    const float* __restrict__ Wh2, const float* __restrict__ bh2,
    float* __restrict__ out, int N)
{
    int lane = threadIdx.x & 63;
    int g = lane & 15;
    int slot = lane >> 4;
    int wslot = (blockIdx.x * blockDim.x + threadIdx.x) >> 6;
    int nwaves = (gridDim.x * blockDim.x) >> 6;

    floatx2 avv[2], w0v[2], w1v[2];
    float b2[4];
    float wh2l, bh1l;
    {
        float t[4];
        ld4(t, att2 + 4 * g);
        avv[0] = floatx2{t[0], t[1]} * (floatx2)LOG2E; avv[1] = floatx2{t[2], t[3]} * (floatx2)LOG2E;
        ld4(t, We2 + 4 * g);       w0v[0] = floatx2{t[0], t[1]}; w0v[1] = floatx2{t[2], t[3]};
        ld4(t, We2 + 64 + 4 * g);  w1v[0] = floatx2{t[0], t[1]}; w1v[1] = floatx2{t[2], t[3]};
        ld4(b2, bias2 + 4 * g);
        wh2l = Wh2[lane];
        bh1l = bh1[lane];
    }

    for (int n = wslot; n < N; n += nwaves) {
        floatx2 xrv[2];
        {
            half4 xh = *(const half4*)(xr2h + (size_t)n * 64 + 4 * g);
            xrv[0] = floatx2{(float)xh[0], (float)xh[1]};
            xrv[1] = floatx2{(float)xh[2], (float)xh[3]};
        }

        int s = off[n], e = off[n + 1];
        float dA = 0.f, dB = 0.f;
        floatx2 accA[2] = {floatx2{0,0}, floatx2{0,0}};
        floatx2 accB[2] = {floatx2{0,0}, floatx2{0,0}};

        for (int p0 = s; p0 < e; p0 += 8) {
            int pA = p0 + slot;
            int pB = p0 + 4 + slot;
            bool vA = (pA < e), vB = (pB < e);
            int2 edA = csr_edge[vA ? pA : s];
            int2 edB = csr_edge[vB ? pB : s];
            union { int u; half2t h; } eAu, eBu;
            eAu.u = edA.y; eBu.u = edB.y;
            float eaxA = (float)eAu.h[0], eayA = (float)eAu.h[1];
            float eaxB = (float)eBu.h[0], eayB = (float)eBu.h[1];

            half4 hvA = *(const half4*)(xl2h + (size_t)edA.x * 64 + 4 * g);
            half4 hvB = *(const half4*)(xl2h + (size_t)edB.x * 64 + 4 * g);
            floatx2 xlA[2], xlB[2];
            xlA[0] = floatx2{(float)hvA[0], (float)hvA[1]};
            xlA[1] = floatx2{(float)hvA[2], (float)hvA[3]};
            xlB[0] = floatx2{(float)hvB[0], (float)hvB[1]};
            xlB[1] = floatx2{(float)hvB[2], (float)hvB[3]};

            floatx2 pvA = floatx2{0,0}, pvB = floatx2{0,0};
#pragma unroll
            for (int k = 0; k < 2; ++k) {
                floatx2 z;
                z = xlA[k] + xrv[k];
                z = __builtin_elementwise_fma((floatx2)eaxA, w0v[k], z);
                z = __builtin_elementwise_fma((floatx2)eayA, w1v[k], z);
                z = __builtin_elementwise_max(z, z * (floatx2)NEG_SLOPE);
                pvA = __builtin_elementwise_fma(z, avv[k], pvA);

                z = xlB[k] + xrv[k];
                z = __builtin_elementwise_fma((floatx2)eaxB, w0v[k], z);
                z = __builtin_elementwise_fma((floatx2)eayB, w1v[k], z);
                z = __builtin_elementwise_max(z, z * (floatx2)NEG_SLOPE);
                pvB = __builtin_elementwise_fma(z, avv[k], pvB);
            }
            float pA_ = pvA.x + pvA.y;
            float pB_ = pvB.x + pvB.y;
            ROW_REDUCE16(pA_);
            ROW_REDUCE16(pB_);
            float evA = vA ? exp2f(pA_) : 0.f;
            float evB = vB ? exp2f(pB_) : 0.f;
            dA += evA; dB += evB;
#pragma unroll
            for (int k = 0; k < 2; ++k) {
                accA[k] = __builtin_elementwise_fma((floatx2)evA, xlA[k], accA[k]);
                accB[k] = __builtin_elementwise_fma((floatx2)evB, xlB[k], accB[k]);
            }
        }

        float acc[4];
        acc[0] = accA[0].x + accB[0].x;  acc[1] = accA[0].y + accB[0].y;
        acc[2] = accA[1].x + accB[1].x;  acc[3] = accA[1].y + accB[1].y;
        float dsum = dA + dB;
#pragma unroll
        for (int i = 0; i < 4; ++i) {
            acc[i] += __shfl_xor(acc[i], 16);
            acc[i] += __shfl_xor(acc[i], 32);
        }
        dsum += __shfl_xor(dsum, 16);
        dsum += __shfl_xor(dsum, 32);

        float r = 1.f / (dsum + 1e-16f);
        float h2[4];
#pragma unroll
        for (int i = 0; i < 4; ++i) h2[i] = fmaxf(fmaf(acc[i], r, b2[i]), 0.f);

        // MLP head
        float t = bh1l;
#pragma unroll
        for (int gp = 0; gp < 16; ++gp) {
            t = fmaf(__shfl(h2[0], gp), Wh1[(4 * gp + 0) * 64 + lane], t);
            t = fmaf(__shfl(h2[1], gp), Wh1[(4 * gp + 1) * 64 + lane], t);
            t = fmaf(__shfl(h2[2], gp), Wh1[(4 * gp + 2) * 64 + lane], t);
            t = fmaf(__shfl(h2[3], gp), Wh1[(4 * gp + 3) * 64 + lane], t);
        }
        t = fmaxf(t, 0.f);
        float prt = t * wh2l;
#pragma unroll
        for (int o = 32; o; o >>= 1) prt += __shfl_xor(prt, o);
        if (lane == 0) out[n] = prt + bh2[0];
    }
}

// ---------------------------------------------------------------------------
extern "C" void kernel_launch(void* const* d_in, const int* in_sizes, int n_in,
                              void* d_out, int out_size, void* d_ws, size_t ws_size,
                              hipStream_t stream) {
    const float* x    = (const float*)d_in[0];
    const int*   ei   = (const int*)d_in[1];
    const float* ea   = (const float*)d_in[2];
    const float* Wl1  = (const float*)d_in[3];
    const float* bl1  = (const float*)d_in[4];
    const float* Wr1  = (const float*)d_in[5];
    const float* br1  = (const float*)d_in[6];
    const float* We1  = (const float*)d_in[7];
    const float* att1 = (const float*)d_in[8];
    const float* bias1= (const float*)d_in[9];
    const float* Wl2  = (const float*)d_in[10];
    const float* bl2  = (const float*)d_in[11];
    const float* Wr2  = (const float*)d_in[12];
    const float* br2  = (const float*)d_in[13];
    const float* We2  = (const float*)d_in[14];
    const float* att2 = (const float*)d_in[15];
    const float* bias2= (const float*)d_in[16];
    const float* Wh1  = (const float*)d_in[17];
    const float* bh1  = (const float*)d_in[18];
    const float* Wh2  = (const float*)d_in[19];
    const float* bh2  = (const float*)d_in[20];

    int N = in_sizes[0] / 6;
    int E = in_sizes[1] / 2;
    const int* srcv = ei;
    const int* dstv = ei + E;

    char* w = (char*)d_ws;
    auto align256 = [](size_t v) { return (v + 255) & ~(size_t)255; };
    _Float16* xlh = (_Float16*)w;
    char* ip = w + align256((size_t)N * 128 * 2);
    _Float16* xrh = (_Float16*)ip; ip += align256((size_t)N * 128 * 2);
    float* h1 = (float*)ip;        ip += align256((size_t)N * 128 * 4);
    _Float16* xl2h = (_Float16*)ip; ip += align256((size_t)N * 64 * 2);
    _Float16* xr2h = (_Float16*)ip; ip += align256((size_t)N * 64 * 2);
    int* deg = (int*)ip;  ip += align256((size_t)N * 4);
    int* off = (int*)ip;  ip += align256((size_t)(N + 1) * 4);
    int* pos = (int*)ip;  ip += align256((size_t)N * 4);
    int B = (N + 511) / 512;
    int* bsum  = (int*)ip; ip += align256((size_t)B * 4);
    int* bpref = (int*)ip; ip += align256((size_t)B * 4);
    int2* csr_edge = (int2*)ip;

    hipMemsetAsync(deg, 0, (size_t)N * sizeof(int), stream);
    prep_kernel<<<((size_t)N * 64 + 255) / 256, 256, 0, stream>>>(
        x, Wl1, bl1, Wr1, br1, xlh, xrh, dstv, deg, N, E);
    scan1_kernel<<<B, 256, 0, stream>>>(deg, bsum, N);
    scan2_kernel<<<1, 256, 0, stream>>>(bsum, bpref, off, B, N);
    scan3_kernel<<<B, 256, 0, stream>>>(deg, bpref, off, pos, N);
    scatter_kernel<<<(E + 255) / 256, 256, 0, stream>>>(
        srcv, dstv, (const float2*)ea, pos, csr_edge, E);
    // persistent-wave aggregation kernels: 3072 blocks = 12288 waves
    c1_kernel<<<3072, 256, 0, stream>>>(
        off, csr_edge, xlh, xrh, We1, att1, bias1, h1, N);
    a2_kernel<<<(N + 63) / 64, 256, 0, stream>>>(
        h1, Wl2, bl2, Wr2, br2, xl2h, xr2h, N);
    c2_kernel<<<3072, 256, 0, stream>>>(
        off, csr_edge, xl2h, xr2h, We2, att2, bias2,
        Wh1, bh1, Wh2, bh2, (float*)d_out, N);
}

// Round 10
// 609.286 us; speedup vs baseline: 1.0397x; 1.0397x over previous
//
#include <hip/hip_runtime.h>
#include <hip/hip_bf16.h>

#define NEG_SLOPE 0.2f
#define LOG2E 1.44269504088896f

typedef _Float16 half8 __attribute__((ext_vector_type(8)));
typedef _Float16 half4 __attribute__((ext_vector_type(4)));
typedef _Float16 half2t __attribute__((ext_vector_type(2)));
typedef float floatx2 __attribute__((ext_vector_type(2)));

__device__ __forceinline__ void ld4(float* d, const float* p) {
    float4 t = *(const float4*)p;
    d[0] = t.x; d[1] = t.y; d[2] = t.z; d[3] = t.w;
}

__device__ __forceinline__ unsigned pack2h(float a, float b) {
    union { half2t h; unsigned u; } pk;
    pk.h[0] = (_Float16)a; pk.h[1] = (_Float16)b;
    return pk.u;
}

// full-rate VALU 16-lane-row all-reduce stage (no DS pipe)
#define DPP_ADD(x, ctrl) \
    ((x) + __int_as_float(__builtin_amdgcn_update_dpp(0, __float_as_int(x), (ctrl), 0xf, 0xf, true)))
#define ROW_REDUCE16(x) do { \
    x = DPP_ADD(x, 0x128); \
    x = DPP_ADD(x, 0x124); \
    x = DPP_ADD(x, 0x122); \
    x = DPP_ADD(x, 0x121); \
} while (0)

// ---------------------------------------------------------------------------
// PREP: layer-1 source+target transforms -> fp16 interleaved tables + histogram.
// ---------------------------------------------------------------------------
__global__ void __launch_bounds__(256) prep_kernel(
    const float* __restrict__ x,
    const float* __restrict__ Wl1, const float* __restrict__ bl1,
    const float* __restrict__ Wr1, const float* __restrict__ br1,
    _Float16* __restrict__ xlh, _Float16* __restrict__ xrh,
    const int* __restrict__ dstv, int* __restrict__ deg,
    int N, int E)
{
    int gt = blockIdx.x * blockDim.x + threadIdx.x;
    int total = blockDim.x * gridDim.x;
    for (int e = gt; e < E; e += total) atomicAdd(&deg[dstv[e]], 1);
    int n = gt >> 6, c = gt & 63;
    if (n >= N) return;
    const float* xrow = x + (size_t)n * 6;
    float l0 = bl1[c], l1 = bl1[64 + c];
    float r0 = br1[c], r1 = br1[64 + c];
#pragma unroll
    for (int f = 0; f < 6; ++f) {
        float xv = xrow[f];
        l0 = fmaf(xv, Wl1[f * 128 + c], l0);
        l1 = fmaf(xv, Wl1[f * 128 + 64 + c], l1);
        r0 = fmaf(xv, Wr1[f * 128 + c], r0);
        r1 = fmaf(xv, Wr1[f * 128 + 64 + c], r1);
    }
    *(unsigned*)(xlh + (size_t)n * 128 + 2 * c) = pack2h(l0, l1);
    *(unsigned*)(xrh + (size_t)n * 128 + 2 * c) = pack2h(r0, r1);
}

// ---------------------------------------------------------------------------
// CSR build: scan + scatter (8B packed edges)
// ---------------------------------------------------------------------------
__global__ void scan1_kernel(const int* __restrict__ deg, int* __restrict__ bsum, int N) {
    __shared__ int red[256];
    int b = blockIdx.x, t = threadIdx.x;
    int i0 = b * 512 + t, i1 = i0 + 256;
    int v = 0;
    if (i0 < N) v += deg[i0];
    if (i1 < N) v += deg[i1];
    red[t] = v;
    __syncthreads();
    for (int s = 128; s > 0; s >>= 1) {
        if (t < s) red[t] += red[t + s];
        __syncthreads();
    }
    if (t == 0) bsum[b] = red[0];
}

__global__ void scan2_kernel(const int* __restrict__ bsum, int* __restrict__ bpref,
                             int* __restrict__ off, int B, int N) {
    __shared__ int lds[1024];
    int t = threadIdx.x;
    for (int i = t; i < B; i += blockDim.x) lds[i] = bsum[i];
    __syncthreads();
    if (t == 0) {
        int run = 0;
        for (int i = 0; i < B; ++i) { int v = lds[i]; lds[i] = run; run += v; }
        off[N] = run;
    }
    __syncthreads();
    for (int i = t; i < B; i += blockDim.x) bpref[i] = lds[i];
}

__global__ void scan3_kernel(const int* __restrict__ deg, const int* __restrict__ bpref,
                             int* __restrict__ off, int* __restrict__ pos, int N) {
    __shared__ int lds[512];
    int b = blockIdx.x, t = threadIdx.x;
    int base = b * 512;
    for (int i = t; i < 512; i += 256) {
        int g = base + i;
        lds[i] = (g < N) ? deg[g] : 0;
    }
    __syncthreads();
    if (t == 0) {
        int run = bpref[b];
        for (int i = 0; i < 512; ++i) { int v = lds[i]; lds[i] = run; run += v; }
    }
    __syncthreads();
    for (int i = t; i < 512; i += 256) {
        int g = base + i;
        if (g < N) { off[g] = lds[i]; pos[g] = lds[i]; }
    }
}

__global__ void scatter_kernel(const int* __restrict__ srcv, const int* __restrict__ dstv,
                               const float2* __restrict__ ea2, int* __restrict__ pos,
                               int2* __restrict__ csr_edge, int E) {
    int e = blockIdx.x * blockDim.x + threadIdx.x;
    if (e >= E) return;
    int d = dstv[e];
    int p = atomicAdd(&pos[d], 1);
    float2 ea = ea2[e];
    int2 v;
    v.x = srcv[e];
    v.y = (int)pack2h(ea.x, ea.y);
    csr_edge[p] = v;
}

// ---------------------------------------------------------------------------
// C1: layer-1 aggregation. Wave per dst node; 8 edges/iter (2 quads x 16
// lanes/edge). DPP row-reduce for logits, packed float2 channel math.
// ---------------------------------------------------------------------------
__global__ void __launch_bounds__(256) c1_kernel(
    const int* __restrict__ off, const int2* __restrict__ csr_edge,
    const _Float16* __restrict__ xlh, const _Float16* __restrict__ xrh,
    const float* __restrict__ We1, const float* __restrict__ att1,
    const float* __restrict__ bias1,
    float* __restrict__ h1, int N)
{
    int wid = (blockIdx.x * blockDim.x + threadIdx.x) >> 6;
    int lane = threadIdx.x & 63;
    if (wid >= N) return;
    int n = wid;
    int g = lane & 15;
    int slot = lane >> 4;

    floatx2 a0v[2], a1v[2], w00v[2], w01v[2], w10v[2], w11v[2];
    {
        float t[4];
        ld4(t, att1 + 4 * g);
        a0v[0] = floatx2{t[0], t[1]} * (floatx2)LOG2E; a0v[1] = floatx2{t[2], t[3]} * (floatx2)LOG2E;
        ld4(t, att1 + 64 + 4 * g);
        a1v[0] = floatx2{t[0], t[1]} * (floatx2)LOG2E; a1v[1] = floatx2{t[2], t[3]} * (floatx2)LOG2E;
        ld4(t, We1 + 4 * g);        w00v[0] = floatx2{t[0], t[1]}; w00v[1] = floatx2{t[2], t[3]};
        ld4(t, We1 + 64 + 4 * g);   w01v[0] = floatx2{t[0], t[1]}; w01v[1] = floatx2{t[2], t[3]};
        ld4(t, We1 + 128 + 4 * g);  w10v[0] = floatx2{t[0], t[1]}; w10v[1] = floatx2{t[2], t[3]};
        ld4(t, We1 + 192 + 4 * g);  w11v[0] = floatx2{t[0], t[1]}; w11v[1] = floatx2{t[2], t[3]};
    }

    floatx2 xr0v[2], xr1v[2];
    {
        half8 xrv = *(const half8*)(xrh + (size_t)n * 128 + 8 * g);
        xr0v[0] = floatx2{(float)xrv[0], (float)xrv[2]};
        xr0v[1] = floatx2{(float)xrv[4], (float)xrv[6]};
        xr1v[0] = floatx2{(float)xrv[1], (float)xrv[3]};
        xr1v[1] = floatx2{(float)xrv[5], (float)xrv[7]};
    }

    int s = off[n], e = off[n + 1];
    floatx2 acc0A[2] = {floatx2{0,0}, floatx2{0,0}}, acc1A[2] = {floatx2{0,0}, floatx2{0,0}};
    floatx2 acc0B[2] = {floatx2{0,0}, floatx2{0,0}}, acc1B[2] = {floatx2{0,0}, floatx2{0,0}};
    float d0A = 0.f, d1A = 0.f, d0B = 0.f, d1B = 0.f;

    for (int p0 = s; p0 < e; p0 += 8) {
        int pA = p0 + slot;
        int pB = p0 + 4 + slot;
        bool vA = (pA < e), vB = (pB < e);
        int2 edA = csr_edge[vA ? pA : s];
        int2 edB = csr_edge[vB ? pB : s];
        union { int u; half2t h; } eAu, eBu;
        eAu.u = edA.y; eBu.u = edB.y;
        float eaxA = (float)eAu.h[0], eayA = (float)eAu.h[1];
        float eaxB = (float)eBu.h[0], eayB = (float)eBu.h[1];

        half8 hvA = *(const half8*)(xlh + (size_t)edA.x * 128 + 8 * g);
        half8 hvB = *(const half8*)(xlh + (size_t)edB.x * 128 + 8 * g);

        floatx2 xl0A[2], xl1A[2], xl0B[2], xl1B[2];
        xl0A[0] = floatx2{(float)hvA[0], (float)hvA[2]};
        xl0A[1] = floatx2{(float)hvA[4], (float)hvA[6]};
        xl1A[0] = floatx2{(float)hvA[1], (float)hvA[3]};
        xl1A[1] = floatx2{(float)hvA[5], (float)hvA[7]};
        xl0B[0] = floatx2{(float)hvB[0], (float)hvB[2]};
        xl0B[1] = floatx2{(float)hvB[4], (float)hvB[6]};
        xl1B[0] = floatx2{(float)hvB[1], (float)hvB[3]};
        xl1B[1] = floatx2{(float)hvB[5], (float)hvB[7]};

        floatx2 pv0A = floatx2{0,0}, pv1A = floatx2{0,0};
        floatx2 pv0B = floatx2{0,0}, pv1B = floatx2{0,0};
#pragma unroll
        for (int k = 0; k < 2; ++k) {
            floatx2 z;
            z = xl0A[k] + xr0v[k];
            z = __builtin_elementwise_fma((floatx2)eaxA, w00v[k], z);
            z = __builtin_elementwise_fma((floatx2)eayA, w10v[k], z);
            z = __builtin_elementwise_max(z, z * (floatx2)NEG_SLOPE);
            pv0A = __builtin_elementwise_fma(z, a0v[k], pv0A);

            z = xl1A[k] + xr1v[k];
            z = __builtin_elementwise_fma((floatx2)eaxA, w01v[k], z);
            z = __builtin_elementwise_fma((floatx2)eayA, w11v[k], z);
            z = __builtin_elementwise_max(z, z * (floatx2)NEG_SLOPE);
            pv1A = __builtin_elementwise_fma(z, a1v[k], pv1A);

            z = xl0B[k] + xr0v[k];
            z = __builtin_elementwise_fma((floatx2)eaxB, w00v[k], z);
            z = __builtin_elementwise_fma((floatx2)eayB, w10v[k], z);
            z = __builtin_elementwise_max(z, z * (floatx2)NEG_SLOPE);
            pv0B = __builtin_elementwise_fma(z, a0v[k], pv0B);

            z = xl1B[k] + xr1v[k];
            z = __builtin_elementwise_fma((floatx2)eaxB, w01v[k], z);
            z = __builtin_elementwise_fma((floatx2)eayB, w11v[k], z);
            z = __builtin_elementwise_max(z, z * (floatx2)NEG_SLOPE);
            pv1B = __builtin_elementwise_fma(z, a1v[k], pv1B);
        }
        float pA0 = pv0A.x + pv0A.y;
        float pA1 = pv1A.x + pv1A.y;
        float pB0 = pv0B.x + pv0B.y;
        float pB1 = pv1B.x + pv1B.y;

        ROW_REDUCE16(pA0);
        ROW_REDUCE16(pA1);
        ROW_REDUCE16(pB0);
        ROW_REDUCE16(pB1);

        float eA0 = vA ? exp2f(pA0) : 0.f;
        float eA1 = vA ? exp2f(pA1) : 0.f;
        float eB0 = vB ? exp2f(pB0) : 0.f;
        float eB1 = vB ? exp2f(pB1) : 0.f;
        d0A += eA0; d1A += eA1;
        d0B += eB0; d1B += eB1;
#pragma unroll
        for (int k = 0; k < 2; ++k) {
            acc0A[k] = __builtin_elementwise_fma((floatx2)eA0, xl0A[k], acc0A[k]);
            acc1A[k] = __builtin_elementwise_fma((floatx2)eA1, xl1A[k], acc1A[k]);
            acc0B[k] = __builtin_elementwise_fma((floatx2)eB0, xl0B[k], acc0B[k]);
            acc1B[k] = __builtin_elementwise_fma((floatx2)eB1, xl1B[k], acc1B[k]);
        }
    }

    float acc0[4], acc1[4];
    acc0[0] = acc0A[0].x + acc0B[0].x;  acc0[1] = acc0A[0].y + acc0B[0].y;
    acc0[2] = acc0A[1].x + acc0B[1].x;  acc0[3] = acc0A[1].y + acc0B[1].y;
    acc1[0] = acc1A[0].x + acc1B[0].x;  acc1[1] = acc1A[0].y + acc1B[0].y;
    acc1[2] = acc1A[1].x + acc1B[1].x;  acc1[3] = acc1A[1].y + acc1B[1].y;
    float d0 = d0A + d0B, d1 = d1A + d1B;
#pragma unroll
    for (int i = 0; i < 4; ++i) {
        acc0[i] += __shfl_xor(acc0[i], 16); acc0[i] += __shfl_xor(acc0[i], 32);
        acc1[i] += __shfl_xor(acc1[i], 16); acc1[i] += __shfl_xor(acc1[i], 32);
    }
    d0 += __shfl_xor(d0, 16); d0 += __shfl_xor(d0, 32);
    d1 += __shfl_xor(d1, 16); d1 += __shfl_xor(d1, 32);

    if (slot == 0) {
        float b0[4], b1[4];
        ld4(b0, bias1 + 4 * g);
        ld4(b1, bias1 + 64 + 4 * g);
        float r0 = 1.f / (d0 + 1e-16f), r1 = 1.f / (d1 + 1e-16f);
        float4 o0, o1;
        o0.x = fmaxf(fmaf(acc0[0], r0, b0[0]), 0.f);
        o0.y = fmaxf(fmaf(acc0[1], r0, b0[1]), 0.f);
        o0.z = fmaxf(fmaf(acc0[2], r0, b0[2]), 0.f);
        o0.w = fmaxf(fmaf(acc0[3], r0, b0[3]), 0.f);
        o1.x = fmaxf(fmaf(acc1[0], r1, b1[0]), 0.f);
        o1.y = fmaxf(fmaf(acc1[1], r1, b1[1]), 0.f);
        o1.z = fmaxf(fmaf(acc1[2], r1, b1[2]), 0.f);
        o1.w = fmaxf(fmaf(acc1[3], r1, b1[3]), 0.f);
        *(float4*)(h1 + (size_t)n * 128 + 4 * g) = o0;
        *(float4*)(h1 + (size_t)n * 128 + 64 + 4 * g) = o1;
    }
}

// ---------------------------------------------------------------------------
// A2: layer-2 node transforms as an LDS-tiled GEMM (no shuffles).
// ---------------------------------------------------------------------------
__global__ void __launch_bounds__(256) a2_kernel(
    const float* __restrict__ h1,
    const float* __restrict__ Wl2, const float* __restrict__ bl2,
    const float* __restrict__ Wr2, const float* __restrict__ br2,
    _Float16* __restrict__ xl2h, _Float16* __restrict__ xr2h, int N)
{
    __shared__ float hs[64 * 128];   // 32 KB
    int tid = threadIdx.x;
    int n0 = blockIdx.x * 64;

    for (int i = tid; i < 64 * 32; i += 256) {
        int row = i >> 5;
        int q = i & 31;
        int n = n0 + row;
        float4 v = (n < N) ? *(const float4*)(h1 + (size_t)n * 128 + q * 4)
                           : make_float4(0.f, 0.f, 0.f, 0.f);
        *(float4*)(hs + row * 128 + q * 4) = v;
    }
    __syncthreads();

    int cslot = tid & 31;
    int jgrp = tid >> 5;
    int c4 = cslot * 4;
    bool isL = (c4 < 64);
    int cc = isL ? c4 : (c4 - 64);
    const float* Wb = (isL ? Wl2 : Wr2) + cc;
    const float* bb = (isL ? bl2 : br2) + cc;
    float4 bias = *(const float4*)bb;

    float acc[8][4];
#pragma unroll
    for (int j = 0; j < 8; ++j) {
        acc[j][0] = bias.x; acc[j][1] = bias.y;
        acc[j][2] = bias.z; acc[j][3] = bias.w;
    }

    const float* hrow = hs + (jgrp * 8) * 128;
#pragma unroll 2
    for (int k4 = 0; k4 < 32; ++k4) {
        float4 w0 = *(const float4*)(Wb + (4 * k4 + 0) * 64);
        float4 w1 = *(const float4*)(Wb + (4 * k4 + 1) * 64);
        float4 w2 = *(const float4*)(Wb + (4 * k4 + 2) * 64);
        float4 w3 = *(const float4*)(Wb + (4 * k4 + 3) * 64);
#pragma unroll
        for (int j = 0; j < 8; ++j) {
            float4 hv = *(const float4*)(hrow + j * 128 + k4 * 4);
            acc[j][0] = fmaf(hv.x, w0.x, acc[j][0]);
            acc[j][1] = fmaf(hv.x, w0.y, acc[j][1]);
            acc[j][2] = fmaf(hv.x, w0.z, acc[j][2]);
            acc[j][3] = fmaf(hv.x, w0.w, acc[j][3]);
            acc[j][0] = fmaf(hv.y, w1.x, acc[j][0]);
            acc[j][1] = fmaf(hv.y, w1.y, acc[j][1]);
            acc[j][2] = fmaf(hv.y, w1.z, acc[j][2]);
            acc[j][3] = fmaf(hv.y, w1.w, acc[j][3]);
            acc[j][0] = fmaf(hv.z, w2.x, acc[j][0]);
            acc[j][1] = fmaf(hv.z, w2.y, acc[j][1]);
            acc[j][2] = fmaf(hv.z, w2.z, acc[j][2]);
            acc[j][3] = fmaf(hv.z, w2.w, acc[j][3]);
            acc[j][0] = fmaf(hv.w, w3.x, acc[j][0]);
            acc[j][1] = fmaf(hv.w, w3.y, acc[j][1]);
            acc[j][2] = fmaf(hv.w, w3.z, acc[j][2]);
            acc[j][3] = fmaf(hv.w, w3.w, acc[j][3]);
        }
    }

    _Float16* outb = isL ? xl2h : xr2h;
#pragma unroll
    for (int j = 0; j < 8; ++j) {
        int n = n0 + jgrp * 8 + j;
        if (n < N) {
            half4 o;
            o[0] = (_Float16)acc[j][0];
            o[1] = (_Float16)acc[j][1];
            o[2] = (_Float16)acc[j][2];
            o[3] = (_Float16)acc[j][3];
            *(half4*)(outb + (size_t)n * 64 + cc) = o;
        }
    }
}

// ---------------------------------------------------------------------------
// C2: layer-2 aggregation + fused MLP head. Wave per node. The head uses a
// per-wave LDS strip (h2 vector) read back as broadcast ds_read_b128 instead
// of 64 serial ds_bpermute shuffles.
// ---------------------------------------------------------------------------
__global__ void __launch_bounds__(256) c2_kernel(
    const int* __restrict__ off, const int2* __restrict__ csr_edge,
    const _Float16* __restrict__ xl2h, const _Float16* __restrict__ xr2h,
    const float* __restrict__ We2, const float* __restrict__ att2,
    const float* __restrict__ bias2,
    const float* __restrict__ Wh1, const float* __restrict__ bh1,
    const float* __restrict__ Wh2, const float* __restrict__ bh2,
    float* __restrict__ out, int N)
{
    __shared__ float h2s[4][64];
    int wid = (blockIdx.x * blockDim.x + threadIdx.x) >> 6;
    int lane = threadIdx.x & 63;
    if (wid >= N) return;
    int n = wid;
    int g = lane & 15;
    int slot = lane >> 4;
    int wv = threadIdx.x >> 6;

    floatx2 avv[2], w0v[2], w1v[2], xrv[2];
    {
        float t[4];
        ld4(t, att2 + 4 * g);
        avv[0] = floatx2{t[0], t[1]} * (floatx2)LOG2E; avv[1] = floatx2{t[2], t[3]} * (floatx2)LOG2E;
        ld4(t, We2 + 4 * g);       w0v[0] = floatx2{t[0], t[1]}; w0v[1] = floatx2{t[2], t[3]};
        ld4(t, We2 + 64 + 4 * g);  w1v[0] = floatx2{t[0], t[1]}; w1v[1] = floatx2{t[2], t[3]};
        half4 xh = *(const half4*)(xr2h + (size_t)n * 64 + 4 * g);
        xrv[0] = floatx2{(float)xh[0], (float)xh[1]};
        xrv[1] = floatx2{(float)xh[2], (float)xh[3]};
    }

    int s = off[n], e = off[n + 1];
    float dA = 0.f, dB = 0.f;
    floatx2 accA[2] = {floatx2{0,0}, floatx2{0,0}};
    floatx2 accB[2] = {floatx2{0,0}, floatx2{0,0}};

    for (int p0 = s; p0 < e; p0 += 8) {
        int pA = p0 + slot;
        int pB = p0 + 4 + slot;
        bool vA = (pA < e), vB = (pB < e);
        int2 edA = csr_edge[vA ? pA : s];
        int2 edB = csr_edge[vB ? pB : s];
        union { int u; half2t h; } eAu, eBu;
        eAu.u = edA.y; eBu.u = edB.y;
        float eaxA = (float)eAu.h[0], eayA = (float)eAu.h[1];
        float eaxB = (float)eBu.h[0], eayB = (float)eBu.h[1];

        half4 hvA = *(const half4*)(xl2h + (size_t)edA.x * 64 + 4 * g);
        half4 hvB = *(const half4*)(xl2h + (size_t)edB.x * 64 + 4 * g);
        floatx2 xlA[2], xlB[2];
        xlA[0] = floatx2{(float)hvA[0], (float)hvA[1]};
        xlA[1] = floatx2{(float)hvA[2], (float)hvA[3]};
        xlB[0] = floatx2{(float)hvB[0], (float)hvB[1]};
        xlB[1] = floatx2{(float)hvB[2], (float)hvB[3]};

        floatx2 pvA = floatx2{0,0}, pvB = floatx2{0,0};
#pragma unroll
        for (int k = 0; k < 2; ++k) {
            floatx2 z;
            z = xlA[k] + xrv[k];
            z = __builtin_elementwise_fma((floatx2)eaxA, w0v[k], z);
            z = __builtin_elementwise_fma((floatx2)eayA, w1v[k], z);
            z = __builtin_elementwise_max(z, z * (floatx2)NEG_SLOPE);
            pvA = __builtin_elementwise_fma(z, avv[k], pvA);

            z = xlB[k] + xrv[k];
            z = __builtin_elementwise_fma((floatx2)eaxB, w0v[k], z);
            z = __builtin_elementwise_fma((floatx2)eayB, w1v[k], z);
            z = __builtin_elementwise_max(z, z * (floatx2)NEG_SLOPE);
            pvB = __builtin_elementwise_fma(z, avv[k], pvB);
        }
        float pA_ = pvA.x + pvA.y;
        float pB_ = pvB.x + pvB.y;
        ROW_REDUCE16(pA_);
        ROW_REDUCE16(pB_);
        float evA = vA ? exp2f(pA_) : 0.f;
        float evB = vB ? exp2f(pB_) : 0.f;
        dA += evA; dB += evB;
#pragma unroll
        for (int k = 0; k < 2; ++k) {
            accA[k] = __builtin_elementwise_fma((floatx2)evA, xlA[k], accA[k]);
            accB[k] = __builtin_elementwise_fma((floatx2)evB, xlB[k], accB[k]);
        }
    }

    float acc[4];
    acc[0] = accA[0].x + accB[0].x;  acc[1] = accA[0].y + accB[0].y;
    acc[2] = accA[1].x + accB[1].x;  acc[3] = accA[1].y + accB[1].y;
    float dsum = dA + dB;
#pragma unroll
    for (int i = 0; i < 4; ++i) {
        acc[i] += __shfl_xor(acc[i], 16);
        acc[i] += __shfl_xor(acc[i], 32);
    }
    dsum += __shfl_xor(dsum, 16);
    dsum += __shfl_xor(dsum, 32);

    float b2[4];
    ld4(b2, bias2 + 4 * g);
    float r = 1.f / (dsum + 1e-16f);
    float h2[4];
#pragma unroll
    for (int i = 0; i < 4; ++i) h2[i] = fmaxf(fmaf(acc[i], r, b2[i]), 0.f);

    // stage h2 in per-wave LDS strip (every lane has the value; slot 0 writes)
    if (slot == 0) {
        float4 o = make_float4(h2[0], h2[1], h2[2], h2[3]);
        *(float4*)&h2s[wv][4 * g] = o;
    }
    // same-wave DS ordering is in-order; compiler fence stops reordering
    asm volatile("" ::: "memory");

    // MLP head via LDS broadcast reads (16 independent b128) + coalesced Wh1
    float t = bh1[lane];
    const float* hvp = h2s[wv];
#pragma unroll
    for (int k = 0; k < 16; ++k) {
        float4 h4 = *(const float4*)(hvp + 4 * k);
        t = fmaf(h4.x, Wh1[(4 * k + 0) * 64 + lane], t);
        t = fmaf(h4.y, Wh1[(4 * k + 1) * 64 + lane], t);
        t = fmaf(h4.z, Wh1[(4 * k + 2) * 64 + lane], t);
        t = fmaf(h4.w, Wh1[(4 * k + 3) * 64 + lane], t);
    }
    t = fmaxf(t, 0.f);
    float prt = t * Wh2[lane];
    ROW_REDUCE16(prt);
    prt += __shfl_xor(prt, 16);
    prt += __shfl_xor(prt, 32);
    if (lane == 0) out[n] = prt + bh2[0];
}

// ---------------------------------------------------------------------------
extern "C" void kernel_launch(void* const* d_in, const int* in_sizes, int n_in,
                              void* d_out, int out_size, void* d_ws, size_t ws_size,
                              hipStream_t stream) {
    const float* x    = (const float*)d_in[0];
    const int*   ei   = (const int*)d_in[1];
    const float* ea   = (const float*)d_in[2];
    const float* Wl1  = (const float*)d_in[3];
    const float* bl1  = (const float*)d_in[4];
    const float* Wr1  = (const float*)d_in[5];
    const float* br1  = (const float*)d_in[6];
    const float* We1  = (const float*)d_in[7];
    const float* att1 = (const float*)d_in[8];
    const float* bias1= (const float*)d_in[9];
    const float* Wl2  = (const float*)d_in[10];
    const float* bl2  = (const float*)d_in[11];
    const float* Wr2  = (const float*)d_in[12];
    const float* br2  = (const float*)d_in[13];
    const float* We2  = (const float*)d_in[14];
    const float* att2 = (const float*)d_in[15];
    const float* bias2= (const float*)d_in[16];
    const float* Wh1  = (const float*)d_in[17];
    const float* bh1  = (const float*)d_in[18];
    const float* Wh2  = (const float*)d_in[19];
    const float* bh2  = (const float*)d_in[20];

    int N = in_sizes[0] / 6;
    int E = in_sizes[1] / 2;
    const int* srcv = ei;
    const int* dstv = ei + E;

    char* w = (char*)d_ws;
    auto align256 = [](size_t v) { return (v + 255) & ~(size_t)255; };
    _Float16* xlh = (_Float16*)w;
    char* ip = w + align256((size_t)N * 128 * 2);
    _Float16* xrh = (_Float16*)ip; ip += align256((size_t)N * 128 * 2);
    float* h1 = (float*)ip;        ip += align256((size_t)N * 128 * 4);
    _Float16* xl2h = (_Float16*)ip; ip += align256((size_t)N * 64 * 2);
    _Float16* xr2h = (_Float16*)ip; ip += align256((size_t)N * 64 * 2);
    int* deg = (int*)ip;  ip += align256((size_t)N * 4);
    int* off = (int*)ip;  ip += align256((size_t)(N + 1) * 4);
    int* pos = (int*)ip;  ip += align256((size_t)N * 4);
    int B = (N + 511) / 512;
    int* bsum  = (int*)ip; ip += align256((size_t)B * 4);
    int* bpref = (int*)ip; ip += align256((size_t)B * 4);
    int2* csr_edge = (int2*)ip;

    hipMemsetAsync(deg, 0, (size_t)N * sizeof(int), stream);
    prep_kernel<<<((size_t)N * 64 + 255) / 256, 256, 0, stream>>>(
        x, Wl1, bl1, Wr1, br1, xlh, xrh, dstv, deg, N, E);
    scan1_kernel<<<B, 256, 0, stream>>>(deg, bsum, N);
    scan2_kernel<<<1, 256, 0, stream>>>(bsum, bpref, off, B, N);
    scan3_kernel<<<B, 256, 0, stream>>>(deg, bpref, off, pos, N);
    scatter_kernel<<<(E + 255) / 256, 256, 0, stream>>>(
        srcv, dstv, (const float2*)ea, pos, csr_edge, E);
    c1_kernel<<<((size_t)N * 64 + 255) / 256, 256, 0, stream>>>(
        off, csr_edge, xlh, xrh, We1, att1, bias1, h1, N);
    a2_kernel<<<(N + 63) / 64, 256, 0, stream>>>(
        h1, Wl2, bl2, Wr2, br2, xl2h, xr2h, N);
    c2_kernel<<<((size_t)N * 64 + 255) / 256, 256, 0, stream>>>(
        off, csr_edge, xl2h, xr2h, We2, att2, bias2,
        Wh1, bh1, Wh2, bh2, (float*)d_out, N);
}

// Round 11
// 577.886 us; speedup vs baseline: 1.0962x; 1.0543x over previous
//
#include <hip/hip_runtime.h>
#include <hip/hip_bf16.h>

#define NEG_SLOPE 0.2f
#define LOG2E 1.44269504088896f

typedef _Float16 half8 __attribute__((ext_vector_type(8)));
typedef _Float16 half4 __attribute__((ext_vector_type(4)));
typedef _Float16 half2t __attribute__((ext_vector_type(2)));
typedef float floatx2 __attribute__((ext_vector_type(2)));

__device__ __forceinline__ void ld4(float* d, const float* p) {
    float4 t = *(const float4*)p;
    d[0] = t.x; d[1] = t.y; d[2] = t.z; d[3] = t.w;
}

__device__ __forceinline__ unsigned pack2h(float a, float b) {
    union { half2t h; unsigned u; } pk;
    pk.h[0] = (_Float16)a; pk.h[1] = (_Float16)b;
    return pk.u;
}

// full-rate VALU 16-lane-row all-reduce stage (no DS pipe)
#define DPP_ADD(x, ctrl) \
    ((x) + __int_as_float(__builtin_amdgcn_update_dpp(0, __float_as_int(x), (ctrl), 0xf, 0xf, true)))
#define ROW_REDUCE16(x) do { \
    x = DPP_ADD(x, 0x128); \
    x = DPP_ADD(x, 0x124); \
    x = DPP_ADD(x, 0x122); \
    x = DPP_ADD(x, 0x121); \
} while (0)

// ---------------------------------------------------------------------------
// PREP: layer-1 source+target transforms -> fp16 interleaved tables + histogram.
// ---------------------------------------------------------------------------
__global__ void __launch_bounds__(256) prep_kernel(
    const float* __restrict__ x,
    const float* __restrict__ Wl1, const float* __restrict__ bl1,
    const float* __restrict__ Wr1, const float* __restrict__ br1,
    _Float16* __restrict__ xlh, _Float16* __restrict__ xrh,
    const int* __restrict__ dstv, int* __restrict__ deg,
    int N, int E)
{
    int gt = blockIdx.x * blockDim.x + threadIdx.x;
    int total = blockDim.x * gridDim.x;
    for (int e = gt; e < E; e += total) atomicAdd(&deg[dstv[e]], 1);
    int n = gt >> 6, c = gt & 63;
    if (n >= N) return;
    const float* xrow = x + (size_t)n * 6;
    float l0 = bl1[c], l1 = bl1[64 + c];
    float r0 = br1[c], r1 = br1[64 + c];
#pragma unroll
    for (int f = 0; f < 6; ++f) {
        float xv = xrow[f];
        l0 = fmaf(xv, Wl1[f * 128 + c], l0);
        l1 = fmaf(xv, Wl1[f * 128 + 64 + c], l1);
        r0 = fmaf(xv, Wr1[f * 128 + c], r0);
        r1 = fmaf(xv, Wr1[f * 128 + 64 + c], r1);
    }
    *(unsigned*)(xlh + (size_t)n * 128 + 2 * c) = pack2h(l0, l1);
    *(unsigned*)(xrh + (size_t)n * 128 + 2 * c) = pack2h(r0, r1);
}

// ---------------------------------------------------------------------------
// CSR build: scan + scatter (8B packed edges)
// ---------------------------------------------------------------------------
__global__ void scan1_kernel(const int* __restrict__ deg, int* __restrict__ bsum, int N) {
    __shared__ int red[256];
    int b = blockIdx.x, t = threadIdx.x;
    int i0 = b * 512 + t, i1 = i0 + 256;
    int v = 0;
    if (i0 < N) v += deg[i0];
    if (i1 < N) v += deg[i1];
    red[t] = v;
    __syncthreads();
    for (int s = 128; s > 0; s >>= 1) {
        if (t < s) red[t] += red[t + s];
        __syncthreads();
    }
    if (t == 0) bsum[b] = red[0];
}

__global__ void scan2_kernel(const int* __restrict__ bsum, int* __restrict__ bpref,
                             int* __restrict__ off, int B, int N) {
    __shared__ int lds[1024];
    int t = threadIdx.x;
    for (int i = t; i < B; i += blockDim.x) lds[i] = bsum[i];
    __syncthreads();
    if (t == 0) {
        int run = 0;
        for (int i = 0; i < B; ++i) { int v = lds[i]; lds[i] = run; run += v; }
        off[N] = run;
    }
    __syncthreads();
    for (int i = t; i < B; i += blockDim.x) bpref[i] = lds[i];
}

__global__ void scan3_kernel(const int* __restrict__ deg, const int* __restrict__ bpref,
                             int* __restrict__ off, int* __restrict__ pos, int N) {
    __shared__ int lds[512];
    int b = blockIdx.x, t = threadIdx.x;
    int base = b * 512;
    for (int i = t; i < 512; i += 256) {
        int g = base + i;
        lds[i] = (g < N) ? deg[g] : 0;
    }
    __syncthreads();
    if (t == 0) {
        int run = bpref[b];
        for (int i = 0; i < 512; ++i) { int v = lds[i]; lds[i] = run; run += v; }
    }
    __syncthreads();
    for (int i = t; i < 512; i += 256) {
        int g = base + i;
        if (g < N) { off[g] = lds[i]; pos[g] = lds[i]; }
    }
}

__global__ void scatter_kernel(const int* __restrict__ srcv, const int* __restrict__ dstv,
                               const float2* __restrict__ ea2, int* __restrict__ pos,
                               int2* __restrict__ csr_edge, int E) {
    int e = blockIdx.x * blockDim.x + threadIdx.x;
    if (e >= E) return;
    int d = dstv[e];
    int p = atomicAdd(&pos[d], 1);
    float2 ea = ea2[e];
    int2 v;
    v.x = srcv[e];
    v.y = (int)pack2h(ea.x, ea.y);
    csr_edge[p] = v;
}

// ---------------------------------------------------------------------------
// C1: layer-1 aggregation. Wave per dst node; 8 edges/iter (2 quads x 16
// lanes/edge). DPP row-reduce for logits, packed float2 channel math.
// h1 written as fp16.
// ---------------------------------------------------------------------------
__global__ void __launch_bounds__(256) c1_kernel(
    const int* __restrict__ off, const int2* __restrict__ csr_edge,
    const _Float16* __restrict__ xlh, const _Float16* __restrict__ xrh,
    const float* __restrict__ We1, const float* __restrict__ att1,
    const float* __restrict__ bias1,
    _Float16* __restrict__ h1h, int N)
{
    int wid = (blockIdx.x * blockDim.x + threadIdx.x) >> 6;
    int lane = threadIdx.x & 63;
    if (wid >= N) return;
    int n = wid;
    int g = lane & 15;
    int slot = lane >> 4;

    floatx2 a0v[2], a1v[2], w00v[2], w01v[2], w10v[2], w11v[2];
    {
        float t[4];
        ld4(t, att1 + 4 * g);
        a0v[0] = floatx2{t[0], t[1]} * (floatx2)LOG2E; a0v[1] = floatx2{t[2], t[3]} * (floatx2)LOG2E;
        ld4(t, att1 + 64 + 4 * g);
        a1v[0] = floatx2{t[0], t[1]} * (floatx2)LOG2E; a1v[1] = floatx2{t[2], t[3]} * (floatx2)LOG2E;
        ld4(t, We1 + 4 * g);        w00v[0] = floatx2{t[0], t[1]}; w00v[1] = floatx2{t[2], t[3]};
        ld4(t, We1 + 64 + 4 * g);   w01v[0] = floatx2{t[0], t[1]}; w01v[1] = floatx2{t[2], t[3]};
        ld4(t, We1 + 128 + 4 * g);  w10v[0] = floatx2{t[0], t[1]}; w10v[1] = floatx2{t[2], t[3]};
        ld4(t, We1 + 192 + 4 * g);  w11v[0] = floatx2{t[0], t[1]}; w11v[1] = floatx2{t[2], t[3]};
    }

    floatx2 xr0v[2], xr1v[2];
    {
        half8 xrv = *(const half8*)(xrh + (size_t)n * 128 + 8 * g);
        xr0v[0] = floatx2{(float)xrv[0], (float)xrv[2]};
        xr0v[1] = floatx2{(float)xrv[4], (float)xrv[6]};
        xr1v[0] = floatx2{(float)xrv[1], (float)xrv[3]};
        xr1v[1] = floatx2{(float)xrv[5], (float)xrv[7]};
    }

    int s = off[n], e = off[n + 1];
    floatx2 acc0A[2] = {floatx2{0,0}, floatx2{0,0}}, acc1A[2] = {floatx2{0,0}, floatx2{0,0}};
    floatx2 acc0B[2] = {floatx2{0,0}, floatx2{0,0}}, acc1B[2] = {floatx2{0,0}, floatx2{0,0}};
    float d0A = 0.f, d1A = 0.f, d0B = 0.f, d1B = 0.f;

    for (int p0 = s; p0 < e; p0 += 8) {
        int pA = p0 + slot;
        int pB = p0 + 4 + slot;
        bool vA = (pA < e), vB = (pB < e);
        int2 edA = csr_edge[vA ? pA : s];
        int2 edB = csr_edge[vB ? pB : s];
        union { int u; half2t h; } eAu, eBu;
        eAu.u = edA.y; eBu.u = edB.y;
        float eaxA = (float)eAu.h[0], eayA = (float)eAu.h[1];
        float eaxB = (float)eBu.h[0], eayB = (float)eBu.h[1];

        half8 hvA = *(const half8*)(xlh + (size_t)edA.x * 128 + 8 * g);
        half8 hvB = *(const half8*)(xlh + (size_t)edB.x * 128 + 8 * g);

        floatx2 xl0A[2], xl1A[2], xl0B[2], xl1B[2];
        xl0A[0] = floatx2{(float)hvA[0], (float)hvA[2]};
        xl0A[1] = floatx2{(float)hvA[4], (float)hvA[6]};
        xl1A[0] = floatx2{(float)hvA[1], (float)hvA[3]};
        xl1A[1] = floatx2{(float)hvA[5], (float)hvA[7]};
        xl0B[0] = floatx2{(float)hvB[0], (float)hvB[2]};
        xl0B[1] = floatx2{(float)hvB[4], (float)hvB[6]};
        xl1B[0] = floatx2{(float)hvB[1], (float)hvB[3]};
        xl1B[1] = floatx2{(float)hvB[5], (float)hvB[7]};

        floatx2 pv0A = floatx2{0,0}, pv1A = floatx2{0,0};
        floatx2 pv0B = floatx2{0,0}, pv1B = floatx2{0,0};
#pragma unroll
        for (int k = 0; k < 2; ++k) {
            floatx2 z;
            z = xl0A[k] + xr0v[k];
            z = __builtin_elementwise_fma((floatx2)eaxA, w00v[k], z);
            z = __builtin_elementwise_fma((floatx2)eayA, w10v[k], z);
            z = __builtin_elementwise_max(z, z * (floatx2)NEG_SLOPE);
            pv0A = __builtin_elementwise_fma(z, a0v[k], pv0A);

            z = xl1A[k] + xr1v[k];
            z = __builtin_elementwise_fma((floatx2)eaxA, w01v[k], z);
            z = __builtin_elementwise_fma((floatx2)eayA, w11v[k], z);
            z = __builtin_elementwise_max(z, z * (floatx2)NEG_SLOPE);
            pv1A = __builtin_elementwise_fma(z, a1v[k], pv1A);

            z = xl0B[k] + xr0v[k];
            z = __builtin_elementwise_fma((floatx2)eaxB, w00v[k], z);
            z = __builtin_elementwise_fma((floatx2)eayB, w10v[k], z);
            z = __builtin_elementwise_max(z, z * (floatx2)NEG_SLOPE);
            pv0B = __builtin_elementwise_fma(z, a0v[k], pv0B);

            z = xl1B[k] + xr1v[k];
            z = __builtin_elementwise_fma((floatx2)eaxB, w01v[k], z);
            z = __builtin_elementwise_fma((floatx2)eayB, w11v[k], z);
            z = __builtin_elementwise_max(z, z * (floatx2)NEG_SLOPE);
            pv1B = __builtin_elementwise_fma(z, a1v[k], pv1B);
        }
        float pA0 = pv0A.x + pv0A.y;
        float pA1 = pv1A.x + pv1A.y;
        float pB0 = pv0B.x + pv0B.y;
        float pB1 = pv1B.x + pv1B.y;

        ROW_REDUCE16(pA0);
        ROW_REDUCE16(pA1);
        ROW_REDUCE16(pB0);
        ROW_REDUCE16(pB1);

        float eA0 = vA ? exp2f(pA0) : 0.f;
        float eA1 = vA ? exp2f(pA1) : 0.f;
        float eB0 = vB ? exp2f(pB0) : 0.f;
        float eB1 = vB ? exp2f(pB1) : 0.f;
        d0A += eA0; d1A += eA1;
        d0B += eB0; d1B += eB1;
#pragma unroll
        for (int k = 0; k < 2; ++k) {
            acc0A[k] = __builtin_elementwise_fma((floatx2)eA0, xl0A[k], acc0A[k]);
            acc1A[k] = __builtin_elementwise_fma((floatx2)eA1, xl1A[k], acc1A[k]);
            acc0B[k] = __builtin_elementwise_fma((floatx2)eB0, xl0B[k], acc0B[k]);
            acc1B[k] = __builtin_elementwise_fma((floatx2)eB1, xl1B[k], acc1B[k]);
        }
    }

    float acc0[4], acc1[4];
    acc0[0] = acc0A[0].x + acc0B[0].x;  acc0[1] = acc0A[0].y + acc0B[0].y;
    acc0[2] = acc0A[1].x + acc0B[1].x;  acc0[3] = acc0A[1].y + acc0B[1].y;
    acc1[0] = acc1A[0].x + acc1B[0].x;  acc1[1] = acc1A[0].y + acc1B[0].y;
    acc1[2] = acc1A[1].x + acc1B[1].x;  acc1[3] = acc1A[1].y + acc1B[1].y;
    float d0 = d0A + d0B, d1 = d1A + d1B;
#pragma unroll
    for (int i = 0; i < 4; ++i) {
        acc0[i] += __shfl_xor(acc0[i], 16); acc0[i] += __shfl_xor(acc0[i], 32);
        acc1[i] += __shfl_xor(acc1[i], 16); acc1[i] += __shfl_xor(acc1[i], 32);
    }
    d0 += __shfl_xor(d0, 16); d0 += __shfl_xor(d0, 32);
    d1 += __shfl_xor(d1, 16); d1 += __shfl_xor(d1, 32);

    if (slot == 0) {
        float b0[4], b1[4];
        ld4(b0, bias1 + 4 * g);
        ld4(b1, bias1 + 64 + 4 * g);
        float r0 = 1.f / (d0 + 1e-16f), r1 = 1.f / (d1 + 1e-16f);
        half4 o0, o1;
        o0[0] = (_Float16)fmaxf(fmaf(acc0[0], r0, b0[0]), 0.f);
        o0[1] = (_Float16)fmaxf(fmaf(acc0[1], r0, b0[1]), 0.f);
        o0[2] = (_Float16)fmaxf(fmaf(acc0[2], r0, b0[2]), 0.f);
        o0[3] = (_Float16)fmaxf(fmaf(acc0[3], r0, b0[3]), 0.f);
        o1[0] = (_Float16)fmaxf(fmaf(acc1[0], r1, b1[0]), 0.f);
        o1[1] = (_Float16)fmaxf(fmaf(acc1[1], r1, b1[1]), 0.f);
        o1[2] = (_Float16)fmaxf(fmaf(acc1[2], r1, b1[2]), 0.f);
        o1[3] = (_Float16)fmaxf(fmaf(acc1[3], r1, b1[3]), 0.f);
        *(half4*)(h1h + (size_t)n * 128 + 4 * g) = o0;
        *(half4*)(h1h + (size_t)n * 128 + 64 + 4 * g) = o1;
    }
}

// ---------------------------------------------------------------------------
// A2: layer-2 node transforms as an LDS-tiled GEMM. h1 read as fp16,
// converted to fp32 during LDS staging (inner loop unchanged).
// ---------------------------------------------------------------------------
__global__ void __launch_bounds__(256) a2_kernel(
    const _Float16* __restrict__ h1h,
    const float* __restrict__ Wl2, const float* __restrict__ bl2,
    const float* __restrict__ Wr2, const float* __restrict__ br2,
    _Float16* __restrict__ xl2h, _Float16* __restrict__ xr2h, int N)
{
    __shared__ float hs[64 * 128];   // 32 KB
    int tid = threadIdx.x;
    int n0 = blockIdx.x * 64;

    // stage 64 rows of h1 (fp16 -> fp32), zero-pad beyond N
    for (int i = tid; i < 64 * 16; i += 256) {
        int row = i >> 4;
        int q = i & 15;            // 16 chunks of 8 halves (16B)
        int n = n0 + row;
        float f[8];
        if (n < N) {
            half8 v = *(const half8*)(h1h + (size_t)n * 128 + q * 8);
#pragma unroll
            for (int j = 0; j < 8; ++j) f[j] = (float)v[j];
        } else {
#pragma unroll
            for (int j = 0; j < 8; ++j) f[j] = 0.f;
        }
        *(float4*)(hs + row * 128 + q * 8)     = make_float4(f[0], f[1], f[2], f[3]);
        *(float4*)(hs + row * 128 + q * 8 + 4) = make_float4(f[4], f[5], f[6], f[7]);
    }
    __syncthreads();

    int cslot = tid & 31;
    int jgrp = tid >> 5;
    int c4 = cslot * 4;
    bool isL = (c4 < 64);
    int cc = isL ? c4 : (c4 - 64);
    const float* Wb = (isL ? Wl2 : Wr2) + cc;
    const float* bb = (isL ? bl2 : br2) + cc;
    float4 bias = *(const float4*)bb;

    float acc[8][4];
#pragma unroll
    for (int j = 0; j < 8; ++j) {
        acc[j][0] = bias.x; acc[j][1] = bias.y;
        acc[j][2] = bias.z; acc[j][3] = bias.w;
    }

    const float* hrow = hs + (jgrp * 8) * 128;
#pragma unroll 2
    for (int k4 = 0; k4 < 32; ++k4) {
        float4 w0 = *(const float4*)(Wb + (4 * k4 + 0) * 64);
        float4 w1 = *(const float4*)(Wb + (4 * k4 + 1) * 64);
        float4 w2 = *(const float4*)(Wb + (4 * k4 + 2) * 64);
        float4 w3 = *(const float4*)(Wb + (4 * k4 + 3) * 64);
#pragma unroll
        for (int j = 0; j < 8; ++j) {
            float4 hv = *(const float4*)(hrow + j * 128 + k4 * 4);
            acc[j][0] = fmaf(hv.x, w0.x, acc[j][0]);
            acc[j][1] = fmaf(hv.x, w0.y, acc[j][1]);
            acc[j][2] = fmaf(hv.x, w0.z, acc[j][2]);
            acc[j][3] = fmaf(hv.x, w0.w, acc[j][3]);
            acc[j][0] = fmaf(hv.y, w1.x, acc[j][0]);
            acc[j][1] = fmaf(hv.y, w1.y, acc[j][1]);
            acc[j][2] = fmaf(hv.y, w1.z, acc[j][2]);
            acc[j][3] = fmaf(hv.y, w1.w, acc[j][3]);
            acc[j][0] = fmaf(hv.z, w2.x, acc[j][0]);
            acc[j][1] = fmaf(hv.z, w2.y, acc[j][1]);
            acc[j][2] = fmaf(hv.z, w2.z, acc[j][2]);
            acc[j][3] = fmaf(hv.z, w2.w, acc[j][3]);
            acc[j][0] = fmaf(hv.w, w3.x, acc[j][0]);
            acc[j][1] = fmaf(hv.w, w3.y, acc[j][1]);
            acc[j][2] = fmaf(hv.w, w3.z, acc[j][2]);
            acc[j][3] = fmaf(hv.w, w3.w, acc[j][3]);
        }
    }

    _Float16* outb = isL ? xl2h : xr2h;
#pragma unroll
    for (int j = 0; j < 8; ++j) {
        int n = n0 + jgrp * 8 + j;
        if (n < N) {
            half4 o;
            o[0] = (_Float16)acc[j][0];
            o[1] = (_Float16)acc[j][1];
            o[2] = (_Float16)acc[j][2];
            o[3] = (_Float16)acc[j][3];
            *(half4*)(outb + (size_t)n * 64 + cc) = o;
        }
    }
}

// ---------------------------------------------------------------------------
// C2: layer-2 aggregation + fused MLP head (R7 shuffle head). Wave per node.
// ---------------------------------------------------------------------------
__global__ void __launch_bounds__(256) c2_kernel(
    const int* __restrict__ off, const int2* __restrict__ csr_edge,
    const _Float16* __restrict__ xl2h, const _Float16* __restrict__ xr2h,
    const float* __restrict__ We2, const float* __restrict__ att2,
    const float* __restrict__ bias2,
    const float* __restrict__ Wh1, const float* __restrict__ bh1,
    const float* __restrict__ Wh2, const float* __restrict__ bh2,
    float* __restrict__ out, int N)
{
    int wid = (blockIdx.x * blockDim.x + threadIdx.x) >> 6;
    int lane = threadIdx.x & 63;
    if (wid >= N) return;
    int n = wid;
    int g = lane & 15;
    int slot = lane >> 4;

    floatx2 avv[2], w0v[2], w1v[2], xrv[2];
    {
        float t[4];
        ld4(t, att2 + 4 * g);
        avv[0] = floatx2{t[0], t[1]} * (floatx2)LOG2E; avv[1] = floatx2{t[2], t[3]} * (floatx2)LOG2E;
        ld4(t, We2 + 4 * g);       w0v[0] = floatx2{t[0], t[1]}; w0v[1] = floatx2{t[2], t[3]};
        ld4(t, We2 + 64 + 4 * g);  w1v[0] = floatx2{t[0], t[1]}; w1v[1] = floatx2{t[2], t[3]};
        half4 xh = *(const half4*)(xr2h + (size_t)n * 64 + 4 * g);
        xrv[0] = floatx2{(float)xh[0], (float)xh[1]};
        xrv[1] = floatx2{(float)xh[2], (float)xh[3]};
    }

    int s = off[n], e = off[n + 1];
    float dA = 0.f, dB = 0.f;
    floatx2 accA[2] = {floatx2{0,0}, floatx2{0,0}};
    floatx2 accB[2] = {floatx2{0,0}, floatx2{0,0}};

    for (int p0 = s; p0 < e; p0 += 8) {
        int pA = p0 + slot;
        int pB = p0 + 4 + slot;
        bool vA = (pA < e), vB = (pB < e);
        int2 edA = csr_edge[vA ? pA : s];
        int2 edB = csr_edge[vB ? pB : s];
        union { int u; half2t h; } eAu, eBu;
        eAu.u = edA.y; eBu.u = edB.y;
        float eaxA = (float)eAu.h[0], eayA = (float)eAu.h[1];
        float eaxB = (float)eBu.h[0], eayB = (float)eBu.h[1];

        half4 hvA = *(const half4*)(xl2h + (size_t)edA.x * 64 + 4 * g);
        half4 hvB = *(const half4*)(xl2h + (size_t)edB.x * 64 + 4 * g);
        floatx2 xlA[2], xlB[2];
        xlA[0] = floatx2{(float)hvA[0], (float)hvA[1]};
        xlA[1] = floatx2{(float)hvA[2], (float)hvA[3]};
        xlB[0] = floatx2{(float)hvB[0], (float)hvB[1]};
        xlB[1] = floatx2{(float)hvB[2], (float)hvB[3]};

        floatx2 pvA = floatx2{0,0}, pvB = floatx2{0,0};
#pragma unroll
        for (int k = 0; k < 2; ++k) {
            floatx2 z;
            z = xlA[k] + xrv[k];
            z = __builtin_elementwise_fma((floatx2)eaxA, w0v[k], z);
            z = __builtin_elementwise_fma((floatx2)eayA, w1v[k], z);
            z = __builtin_elementwise_max(z, z * (floatx2)NEG_SLOPE);
            pvA = __builtin_elementwise_fma(z, avv[k], pvA);

            z = xlB[k] + xrv[k];
            z = __builtin_elementwise_fma((floatx2)eaxB, w0v[k], z);
            z = __builtin_elementwise_fma((floatx2)eayB, w1v[k], z);
            z = __builtin_elementwise_max(z, z * (floatx2)NEG_SLOPE);
            pvB = __builtin_elementwise_fma(z, avv[k], pvB);
        }
        float pA_ = pvA.x + pvA.y;
        float pB_ = pvB.x + pvB.y;
        ROW_REDUCE16(pA_);
        ROW_REDUCE16(pB_);
        float evA = vA ? exp2f(pA_) : 0.f;
        float evB = vB ? exp2f(pB_) : 0.f;
        dA += evA; dB += evB;
#pragma unroll
        for (int k = 0; k < 2; ++k) {
            accA[k] = __builtin_elementwise_fma((floatx2)evA, xlA[k], accA[k]);
            accB[k] = __builtin_elementwise_fma((floatx2)evB, xlB[k], accB[k]);
        }
    }

    float acc[4];
    acc[0] = accA[0].x + accB[0].x;  acc[1] = accA[0].y + accB[0].y;
    acc[2] = accA[1].x + accB[1].x;  acc[3] = accA[1].y + accB[1].y;
    float dsum = dA + dB;
#pragma unroll
    for (int i = 0; i < 4; ++i) {
        acc[i] += __shfl_xor(acc[i], 16);
        acc[i] += __shfl_xor(acc[i], 32);
    }
    dsum += __shfl_xor(dsum, 16);
    dsum += __shfl_xor(dsum, 32);

    float b2[4];
    ld4(b2, bias2 + 4 * g);
    float r = 1.f / (dsum + 1e-16f);
    float h2[4];
#pragma unroll
    for (int i = 0; i < 4; ++i) h2[i] = fmaxf(fmaf(acc[i], r, b2[i]), 0.f);

    // MLP head
    float t = bh1[lane];
#pragma unroll
    for (int gp = 0; gp < 16; ++gp) {
        t = fmaf(__shfl(h2[0], gp), Wh1[(4 * gp + 0) * 64 + lane], t);
        t = fmaf(__shfl(h2[1], gp), Wh1[(4 * gp + 1) * 64 + lane], t);
        t = fmaf(__shfl(h2[2], gp), Wh1[(4 * gp + 2) * 64 + lane], t);
        t = fmaf(__shfl(h2[3], gp), Wh1[(4 * gp + 3) * 64 + lane], t);
    }
    t = fmaxf(t, 0.f);
    float prt = t * Wh2[lane];
#pragma unroll
    for (int o = 32; o; o >>= 1) prt += __shfl_xor(prt, o);
    if (lane == 0) out[n] = prt + bh2[0];
}

// ---------------------------------------------------------------------------
extern "C" void kernel_launch(void* const* d_in, const int* in_sizes, int n_in,
                              void* d_out, int out_size, void* d_ws, size_t ws_size,
                              hipStream_t stream) {
    const float* x    = (const float*)d_in[0];
    const int*   ei   = (const int*)d_in[1];
    const float* ea   = (const float*)d_in[2];
    const float* Wl1  = (const float*)d_in[3];
    const float* bl1  = (const float*)d_in[4];
    const float* Wr1  = (const float*)d_in[5];
    const float* br1  = (const float*)d_in[6];
    const float* We1  = (const float*)d_in[7];
    const float* att1 = (const float*)d_in[8];
    const float* bias1= (const float*)d_in[9];
    const float* Wl2  = (const float*)d_in[10];
    const float* bl2  = (const float*)d_in[11];
    const float* Wr2  = (const float*)d_in[12];
    const float* br2  = (const float*)d_in[13];
    const float* We2  = (const float*)d_in[14];
    const float* att2 = (const float*)d_in[15];
    const float* bias2= (const float*)d_in[16];
    const float* Wh1  = (const float*)d_in[17];
    const float* bh1  = (const float*)d_in[18];
    const float* Wh2  = (const float*)d_in[19];
    const float* bh2  = (const float*)d_in[20];

    int N = in_sizes[0] / 6;
    int E = in_sizes[1] / 2;
    const int* srcv = ei;
    const int* dstv = ei + E;

    char* w = (char*)d_ws;
    auto align256 = [](size_t v) { return (v + 255) & ~(size_t)255; };
    _Float16* xlh = (_Float16*)w;
    char* ip = w + align256((size_t)N * 128 * 2);
    _Float16* xrh = (_Float16*)ip; ip += align256((size_t)N * 128 * 2);
    _Float16* h1h = (_Float16*)ip; ip += align256((size_t)N * 128 * 2);
    _Float16* xl2h = (_Float16*)ip; ip += align256((size_t)N * 64 * 2);
    _Float16* xr2h = (_Float16*)ip; ip += align256((size_t)N * 64 * 2);
    int* deg = (int*)ip;  ip += align256((size_t)N * 4);
    int* off = (int*)ip;  ip += align256((size_t)(N + 1) * 4);
    int* pos = (int*)ip;  ip += align256((size_t)N * 4);
    int B = (N + 511) / 512;
    int* bsum  = (int*)ip; ip += align256((size_t)B * 4);
    int* bpref = (int*)ip; ip += align256((size_t)B * 4);
    int2* csr_edge = (int2*)ip;

    hipMemsetAsync(deg, 0, (size_t)N * sizeof(int), stream);
    prep_kernel<<<((size_t)N * 64 + 255) / 256, 256, 0, stream>>>(
        x, Wl1, bl1, Wr1, br1, xlh, xrh, dstv, deg, N, E);
    scan1_kernel<<<B, 256, 0, stream>>>(deg, bsum, N);
    scan2_kernel<<<1, 256, 0, stream>>>(bsum, bpref, off, B, N);
    scan3_kernel<<<B, 256, 0, stream>>>(deg, bpref, off, pos, N);
    scatter_kernel<<<(E + 255) / 256, 256, 0, stream>>>(
        srcv, dstv, (const float2*)ea, pos, csr_edge, E);
    c1_kernel<<<((size_t)N * 64 + 255) / 256, 256, 0, stream>>>(
        off, csr_edge, xlh, xrh, We1, att1, bias1, h1h, N);
    a2_kernel<<<(N + 63) / 64, 256, 0, stream>>>(
        h1h, Wl2, bl2, Wr2, br2, xl2h, xr2h, N);
    c2_kernel<<<((size_t)N * 64 + 255) / 256, 256, 0, stream>>>(
        off, csr_edge, xl2h, xr2h, We2, att2, bias2,
        Wh1, bh1, Wh2, bh2, (float*)d_out, N);
}